// Round 3
// baseline (353.542 us; speedup 1.0000x reference)
//
#include <hip/hip_runtime.h>

typedef __bf16 bf16;
typedef bf16 bf16x4 __attribute__((ext_vector_type(4)));
typedef bf16 bf16x8 __attribute__((ext_vector_type(8)));
typedef float f32x4 __attribute__((ext_vector_type(4)));

#define NND 98      // landmarks
#define KNB 10      // neighbors per node
#define NH 4        // heads
#define CIN 256
#define HC 64
#define XROW_B 528  // bytes per x row in LDS (264 bf16: 256 data + 8 pad), 16B-aligned stride
#define CROW_E 136  // bf16 elems per C row in LDS (128 data + 8 pad), 16B-aligned stride

static __device__ __forceinline__ unsigned short bf16_bits(float f) {
  __bf16 b = (__bf16)f;
  union { __bf16 b; unsigned short u; } cv; cv.b = b;
  return cv.u;
}
static __device__ __forceinline__ float bits_to_f32(unsigned int hi16) {
  union { unsigned int u; float f; } cv; cv.u = hi16 << 16;
  return cv.f;
}

// Pack W [H][2][CIN][HC] fp32 -> MFMA B-fragment order, bf16:
// Wp[hs][kt(8)][nt(4)][lane(64)][8]  with B[k = kt*32 + (lane>>4)*8 + j][n = nt*16 + (lane&15)]
__global__ __launch_bounds__(256) void prep_wp_kernel(const float* __restrict__ W,
                                                      bf16* __restrict__ Wp) {
  int t = blockIdx.x * 256 + threadIdx.x;
  if (t >= 8 * 8 * 4 * 64) return;
  int lane = t & 63;
  int nt = (t >> 6) & 3;
  int kt = (t >> 8) & 7;
  int hs = t >> 11;
  int n = nt * 16 + (lane & 15);
  int kb = kt * 32 + (lane >> 4) * 8;
  const float* src = W + (hs * CIN + kb) * HC + n;
  bf16x8 v;
#pragma unroll
  for (int j = 0; j < 8; ++j) v[j] = (bf16)src[j * HC];
  *(bf16x8*)(Wp + (long long)t * 8) = v;
}

// One block per batch item b; all 4 heads. 1024 threads = 16 waves.
// GEMM wave wv: wh = wv&3 (head), wm = wv>>2 (M-group of 2 tiles).
__global__ __launch_bounds__(1024, 4) void semgconv_kernel(
    const float* __restrict__ x, const float* __restrict__ e,
    const float* __restrict__ bias, const int* __restrict__ cols,
    const bf16* __restrict__ Wp, float* __restrict__ out) {
  // union region: x tile (112 x 528 B) during GEMM, then per-head C tile (112 x 136 bf16)
  __shared__ __align__(16) unsigned char reg0[112 * XROW_B];  // 59136 B
  __shared__ unsigned int pk_lds[NND * KNB];  // 3920 B: (col<<16)|bf16(w) for current head
  __shared__ unsigned short cols_lds[NND * KNB];  // 1960 B
  __shared__ float diag_lds[NND];  // 392 B   -> total 65408 B

  const int tid = threadIdx.x;
  const int b = blockIdx.x;

  // ---- phase 0: neighbor indices -> LDS (shared by all heads) ----
  if (tid < NND) {
    const int* cp = cols + tid * KNB;
#pragma unroll
    for (int j = 0; j < KNB; ++j) cols_lds[tid * KNB + j] = (unsigned short)cp[j];
  }

  // ---- phase 1: stage x[b] -> LDS bf16 row-major, rows 98..111 zero ----
  {
    const float* xb = x + (long long)b * NND * CIN;
#pragma unroll
    for (int it = 0; it < 7; ++it) {
      int idx = tid + it * 1024;         // 112*64 float4-chunks
      int n = idx >> 6;
      int c4 = (idx & 63) << 2;
      f32x4 v = {0.f, 0.f, 0.f, 0.f};
      if (n < NND) v = *(const f32x4*)(xb + n * CIN + c4);
      bf16x4 bv;
      bv[0] = (bf16)v[0]; bv[1] = (bf16)v[1]; bv[2] = (bf16)v[2]; bv[3] = (bf16)v[3];
      *(bf16x4*)(reg0 + n * XROW_B + c4 * 2) = bv;
    }
  }
  __syncthreads();

  // ---- phase 2: MFMA GEMM [112x256 bf16] @ [256x512 bf16] -> fp32 acc ----
  const int lane = tid & 63;
  const int wv = tid >> 6;
  const int wh = wv & 3;   // head
  const int wm = wv >> 2;  // M-group: tiles {2wm, 2wm+1}, wm=3 -> tile 6 only
  const int mt0 = wm * 2;

  f32x4 acc[2][8] = {};  // [im][q], q = s*4+nt -> cols q*16 .. q*16+15 of head wh
  const unsigned char* aptr = reg0 + (mt0 * 16 + (lane & 15)) * XROW_B + (lane >> 4) * 16;
  const bf16* wpl = Wp + ((long long)(wh * 2) * (8 * 4 * 64) + lane) * 8;  // hs = wh*2

#pragma unroll
  for (int kt = 0; kt < 8; ++kt) {
    bf16x8 afr[2];
#pragma unroll
    for (int im = 0; im < 2; ++im)
      if (mt0 + im < 7)
        afr[im] = *(const bf16x8*)(aptr + im * (16 * XROW_B) + kt * 64);
    // first head-half (s=0): q = 0..3
    {
      bf16x8 bfr[4];
#pragma unroll
      for (int nt = 0; nt < 4; ++nt)
        bfr[nt] = *(const bf16x8*)(wpl + ((kt * 4 + nt) * 64) * 8);
#pragma unroll
      for (int im = 0; im < 2; ++im)
        if (mt0 + im < 7)
#pragma unroll
          for (int nt = 0; nt < 4; ++nt)
            acc[im][nt] = __builtin_amdgcn_mfma_f32_16x16x32_bf16(afr[im], bfr[nt],
                                                                  acc[im][nt], 0, 0, 0);
    }
    // second head-half (s=1): q = 4..7
    {
      bf16x8 bfr[4];
#pragma unroll
      for (int nt = 0; nt < 4; ++nt)
        bfr[nt] = *(const bf16x8*)(wpl + ((8 * 4 + kt * 4 + nt) * 64) * 8);
#pragma unroll
      for (int im = 0; im < 2; ++im)
        if (mt0 + im < 7)
#pragma unroll
          for (int nt = 0; nt < 4; ++nt)
            acc[im][4 + nt] = __builtin_amdgcn_mfma_f32_16x16x32_bf16(afr[im], bfr[nt],
                                                                      acc[im][4 + nt], 0, 0, 0);
    }
  }
  __syncthreads();  // all A-frag reads done; reg0 reusable as C

  // ---- epilogue: 4 per-head rounds ----
  bf16* C = (bf16*)reg0;
  const int grow = tid >> 3;        // 0..127: node row (active < 98)
  const int gch = (tid & 7) * 8;    // 8 channels per thread

  for (int h = 0; h < NH; ++h) {
    // per-head softmax (threads 0..97): pack (col, bf16 w) into one u32
    if (tid < NND) {
      const int i = tid;
      const float* ep = e + (h * NND + i) * KNB;
      float ev[KNB];
      float mx = -3.0e38f;
#pragma unroll
      for (int j = 0; j < KNB; ++j) { ev[j] = ep[j]; mx = fmaxf(mx, ev[j]); }
      float s = 0.f;
#pragma unroll
      for (int j = 0; j < KNB; ++j) { ev[j] = __expf(ev[j] - mx); s += ev[j]; }
      const float inv = 1.f / s;
      float dg = 0.f;
#pragma unroll
      for (int j = 0; j < KNB; ++j) {
        float wvv = ev[j] * inv;
        unsigned int cj = (unsigned int)cols_lds[i * KNB + j];
        if ((int)cj == i) { dg = wvv; wvv = 0.f; }
        pk_lds[i * KNB + j] = (cj << 16) | (unsigned int)bf16_bits(wvv);
      }
      diag_lds[i] = dg;
    }
    // C-write: waves of head h dump their acc (bf16) into LDS
    if (wh == h) {
#pragma unroll
      for (int im = 0; im < 2; ++im) {
        int mt = mt0 + im;
        if (mt < 7) {
          int rowb = mt * 16 + (lane >> 4) * 4;
#pragma unroll
          for (int q = 0; q < 8; ++q) {
            int col = q * 16 + (lane & 15);
#pragma unroll
            for (int r = 0; r < 4; ++r)
              C[(rowb + r) * CROW_E + col] = (bf16)acc[im][q][r];
          }
        }
      }
    }
    __syncthreads();

    // gather-aggregate + bias: 8 threads/row, bf16x8 per read, single pass
    if (grow < NND) {
      float av[8];
      {
        f32x4 b0 = *(const f32x4*)(bias + h * HC + gch);
        f32x4 b1 = *(const f32x4*)(bias + h * HC + gch + 4);
        float dg = diag_lds[grow];
        bf16x8 c0 = *(const bf16x8*)(C + grow * CROW_E + gch);
#pragma unroll
        for (int k = 0; k < 4; ++k) av[k] = b0[k] + dg * (float)c0[k];
#pragma unroll
        for (int k = 0; k < 4; ++k) av[4 + k] = b1[k] + dg * (float)c0[4 + k];
      }
      unsigned int pk[KNB];
#pragma unroll
      for (int j = 0; j < KNB; ++j) pk[j] = pk_lds[grow * KNB + j];
#pragma unroll
      for (int j = 0; j < KNB; ++j) {
        int cj = (int)(pk[j] >> 16);
        float wj = bits_to_f32(pk[j] & 0xFFFFu);
        bf16x8 c1 = *(const bf16x8*)(C + cj * CROW_E + HC + gch);
#pragma unroll
        for (int k = 0; k < 8; ++k) av[k] += wj * (float)c1[k];
      }
      float* outp = out + (long long)b * NND * (NH * HC) + (long long)grow * (NH * HC) + h * HC + gch;
      f32x4 o0, o1;
#pragma unroll
      for (int k = 0; k < 4; ++k) { o0[k] = av[k]; o1[k] = av[4 + k]; }
      *(f32x4*)outp = o0;
      *(f32x4*)(outp + 4) = o1;
    }
    __syncthreads();  // protect C/pk before next round overwrites
  }
}

extern "C" void kernel_launch(void* const* d_in, const int* in_sizes, int n_in,
                              void* d_out, int out_size, void* d_ws, size_t ws_size,
                              hipStream_t stream) {
  const float* x    = (const float*)d_in[0];
  const float* W    = (const float*)d_in[1];
  const float* e    = (const float*)d_in[2];
  const float* bias = (const float*)d_in[3];
  // d_in[4] = rows: unused (fixed pattern: row i owns edges i*K .. i*K+K-1)
  const int* cols   = (const int*)d_in[5];
  float* out        = (float*)d_out;
  bf16* Wp          = (bf16*)d_ws;   // 131072 bf16 = 256 KiB of scratch

  int B = in_sizes[0] / (NND * CIN);  // 1024

  prep_wp_kernel<<<64, 256, 0, stream>>>(W, Wp);
  semgconv_kernel<<<B, 1024, 0, stream>>>(x, e, bias, cols, Wp, out);
}

// Round 4
// 264.666 us; speedup vs baseline: 1.3358x; 1.3358x over previous
//
#include <hip/hip_runtime.h>

typedef __bf16 bf16;
typedef bf16 bf16x4 __attribute__((ext_vector_type(4)));
typedef bf16 bf16x8 __attribute__((ext_vector_type(8)));
typedef float f32x4 __attribute__((ext_vector_type(4)));

#define NND 98      // landmarks
#define KNB 10      // neighbors per node
#define NH 4        // heads
#define CIN 256
#define HC 64
#define XROW_B 528   // bytes per x row in LDS (264 bf16: 256 data + 8 pad), 16B-aligned
#define C1TS 232     // bf16 stride of C1^T rows (224 + 8 pad); 464 B = 16B-aligned, 20-dword bank skew
#define M2K 224      // stacked-K: h0 at k=0..97 (pad to 112), h1 at k=112..209 (pad to 224)
#define M2ROWS 112

// ws layout (bytes):
//   [0, 262144)           Wp   : bf16 GEMM1 B-fragments
//   [262144, 462848)      M2d  : bf16 dense [NH][112][224] scatter target
//   [462848, 663552)      M2p  : bf16 GEMM2 A-fragments [NH][7 mt][7 kt][64 lane][8]
#define WS_M2D_OFF 262144
#define WS_M2P_OFF 462848

// ---- prep 1: pack W [H][2][CIN][HC] fp32 -> GEMM1 B-fragment order (known-good) ----
__global__ __launch_bounds__(256) void prep_wp_kernel(const float* __restrict__ W,
                                                      bf16* __restrict__ Wp) {
  int t = blockIdx.x * 256 + threadIdx.x;
  if (t >= 8 * 8 * 4 * 64) return;
  int lane = t & 63;
  int nt = (t >> 6) & 3;
  int kt = (t >> 8) & 7;
  int hs = t >> 11;
  int n = nt * 16 + (lane & 15);
  int kb = kt * 32 + (lane >> 4) * 8;
  const float* src = W + (hs * CIN + kb) * HC + n;
  bf16x8 v;
#pragma unroll
  for (int j = 0; j < 8; ++j) v[j] = (bf16)src[j * HC];
  *(bf16x8*)(Wp + (long long)t * 8) = v;
}

// ---- prep 2: zero M2d (ws is poisoned 0xAA every launch) ----
__global__ __launch_bounds__(256) void prep_zero_kernel(unsigned int* __restrict__ M2d_u32) {
  int t = blockIdx.x * 256 + threadIdx.x;
  if (t < NH * M2ROWS * M2K / 2) M2d_u32[t] = 0u;
}

// ---- prep 3: per-(h,i) softmax over K edge logits, scatter into M2d ----
// M2d[h][i][i] = diag (A[i,i]); M2d[h][i][112+cj] = softmax weight (0 for self-edge slot)
__global__ __launch_bounds__(256) void prep_scatter_kernel(const float* __restrict__ e,
                                                           const int* __restrict__ cols,
                                                           bf16* __restrict__ M2d) {
  int t = blockIdx.x * 256 + threadIdx.x;
  if (t >= NH * NND) return;
  int h = t / NND, i = t % NND;
  const float* ep = e + (h * NND + i) * KNB;
  const int* cp = cols + i * KNB;
  float ev[KNB]; int cv[KNB];
  float mx = -3.0e38f;
#pragma unroll
  for (int j = 0; j < KNB; ++j) { ev[j] = ep[j]; cv[j] = cp[j]; mx = fmaxf(mx, ev[j]); }
  float s = 0.f;
#pragma unroll
  for (int j = 0; j < KNB; ++j) { ev[j] = __expf(ev[j] - mx); s += ev[j]; }
  const float inv = 1.f / s;
  bf16* row = M2d + ((long long)h * M2ROWS + i) * M2K;
  float dg = 0.f;
#pragma unroll
  for (int j = 0; j < KNB; ++j) {
    float wv = ev[j] * inv;
    if (cv[j] == i) { dg = wv; }          // self-edge feeds the diagonal (scales h0)
    else            { row[112 + cv[j]] = (bf16)wv; }
  }
  row[i] = (bf16)dg;
}

// ---- prep 4: pack M2d -> GEMM2 A-fragment order [h][mt][kt][lane][8] ----
__global__ __launch_bounds__(256) void prep_m2p_kernel(const bf16* __restrict__ M2d,
                                                       bf16* __restrict__ M2p) {
  int t = blockIdx.x * 256 + threadIdx.x;
  if (t >= NH * 7 * 7 * 64) return;
  int lane = t & 63;
  int u = t >> 6;
  int kt = u % 7; u /= 7;
  int mt = u % 7;
  int h = u / 7;
  int m = mt * 16 + (lane & 15);
  int kb = kt * 32 + (lane >> 4) * 8;
  const bf16* src = M2d + ((long long)h * M2ROWS + m) * M2K + kb;
  bf16x8 v = *(const bf16x8*)src;
  *(bf16x8*)(M2p + (long long)t * 8) = v;
}

// ---- main: one block per batch item, 1024 threads = 16 waves ----
__global__ __launch_bounds__(1024, 4) void semgconv_kernel(
    const float* __restrict__ x, const float* __restrict__ bias,
    const bf16* __restrict__ Wp, const bf16* __restrict__ M2p,
    float* __restrict__ out) {
  // union: x tile (112 x 528 B) during GEMM1, then 2 heads' C1^T (2 x 64 x 232 bf16)
  __shared__ __align__(16) unsigned char reg0[2 * 64 * C1TS * 2];  // 59392 B >= 59136

  const int tid = threadIdx.x;
  const int b = blockIdx.x;
  const int lane = tid & 63;
  const int wv = tid >> 6;
  const int wh = wv & 3;   // GEMM1: head of this wave
  const int wm = wv >> 2;  // GEMM1: M-group (tiles 2wm, 2wm+1)
  const int mt0 = wm * 2;

  // ---- phase 1: stage x[b] -> LDS bf16 row-major, rows 98..111 zero ----
  {
    const float* xb = x + (long long)b * NND * CIN;
#pragma unroll
    for (int it = 0; it < 7; ++it) {
      int idx = tid + it * 1024;         // 112*64 float4-chunks
      int n = idx >> 6;
      int c4 = (idx & 63) << 2;
      f32x4 v = {0.f, 0.f, 0.f, 0.f};
      if (n < NND) v = *(const f32x4*)(xb + n * CIN + c4);
      bf16x4 bv;
      bv[0] = (bf16)v[0]; bv[1] = (bf16)v[1]; bv[2] = (bf16)v[2]; bv[3] = (bf16)v[3];
      *(bf16x4*)(reg0 + n * XROW_B + c4 * 2) = bv;
    }
  }
  __syncthreads();

  // ---- phase 2: GEMM1  [112x256 bf16] @ [256x512 bf16] -> fp32 acc (known-good) ----
  f32x4 acc[2][8] = {};  // [im][q]: q<4 -> h0 cols q*16.., q>=4 -> h1 cols (q-4)*16..
  const unsigned char* aptr = reg0 + (mt0 * 16 + (lane & 15)) * XROW_B + (lane >> 4) * 16;
  const bf16* wpl = Wp + ((long long)(wh * 2) * (8 * 4 * 64) + lane) * 8;

#pragma unroll
  for (int kt = 0; kt < 8; ++kt) {
    bf16x8 afr[2];
#pragma unroll
    for (int im = 0; im < 2; ++im)
      if (mt0 + im < 7)
        afr[im] = *(const bf16x8*)(aptr + im * (16 * XROW_B) + kt * 64);
    {
      bf16x8 bfr[4];
#pragma unroll
      for (int nt = 0; nt < 4; ++nt)
        bfr[nt] = *(const bf16x8*)(wpl + ((kt * 4 + nt) * 64) * 8);
#pragma unroll
      for (int im = 0; im < 2; ++im)
        if (mt0 + im < 7)
#pragma unroll
          for (int nt = 0; nt < 4; ++nt)
            acc[im][nt] = __builtin_amdgcn_mfma_f32_16x16x32_bf16(afr[im], bfr[nt],
                                                                  acc[im][nt], 0, 0, 0);
    }
    {
      bf16x8 bfr[4];
#pragma unroll
      for (int nt = 0; nt < 4; ++nt)
        bfr[nt] = *(const bf16x8*)(wpl + ((8 * 4 + kt * 4 + nt) * 64) * 8);
#pragma unroll
      for (int im = 0; im < 2; ++im)
        if (mt0 + im < 7)
#pragma unroll
          for (int nt = 0; nt < 4; ++nt)
            acc[im][4 + nt] = __builtin_amdgcn_mfma_f32_16x16x32_bf16(afr[im], bfr[nt],
                                                                      acc[im][4 + nt], 0, 0, 0);
    }
  }
  __syncthreads();  // all A-frag reads done; reg0 reusable as C1^T

  // ---- phases 3/4: two head-pair rounds: C1^T write, then GEMM2 + bias + store ----
  bf16* C1T = (bf16*)reg0;

  for (int r = 0; r < 2; ++r) {
    // C1^T write: waves of heads {2r, 2r+1} dump acc transposed (channel-major, stacked-k)
    if ((wh >> 1) == r) {
      bf16* ct = C1T + (wh & 1) * (64 * C1TS);
#pragma unroll
      for (int im = 0; im < 2; ++im) {
        int mt = mt0 + im;
        if (mt < 7) {
          int kb = mt * 16 + ((lane >> 4) * 4);   // node base (quad*4), multiple of 4
#pragma unroll
          for (int q = 0; q < 8; ++q) {
            int ch = (q & 3) * 16 + (lane & 15);
            int kk = (q >> 2) * 112 + kb;         // h0 -> k=node, h1 -> k=112+node
            bf16x4 v;
            v[0] = (bf16)acc[im][q][0];
            v[1] = (bf16)acc[im][q][1];
            v[2] = (bf16)acc[im][q][2];
            v[3] = (bf16)acc[im][q][3];
            *(bf16x4*)(ct + ch * C1TS + kk) = v;  // 8B-aligned b64 write
          }
        }
      }
    }
    __syncthreads();

    // GEMM2: out_tile[mt][nt] (16x16) = sum_kt M2[mt][kt] (A, global) * C1[kt][nt] (B, LDS)
    for (int t = wv; t < 56; t += 16) {
      int hl = t / 28;               // head within pair
      int rem = t % 28;
      int mt = rem >> 2, nt = rem & 3;
      int h = r * 2 + hl;
      const bf16* ct = C1T + hl * (64 * C1TS)
                     + (nt * 16 + (lane & 15)) * C1TS + ((lane >> 4) * 8);
      const bf16* ap = M2p + (((long long)(h * 7 + mt) * 7) * 64 + lane) * 8;
      f32x4 a2 = {0.f, 0.f, 0.f, 0.f};
#pragma unroll
      for (int kt = 0; kt < 7; ++kt) {
        bf16x8 af = *(const bf16x8*)(ap + (long long)kt * (64 * 8));
        bf16x8 bfv = *(const bf16x8*)(ct + kt * 32);
        a2 = __builtin_amdgcn_mfma_f32_16x16x32_bf16(af, bfv, a2, 0, 0, 0);
      }
      // C/D layout: col = lane&15, row = quad*4 + r4
      int colg = h * HC + nt * 16 + (lane & 15);
      float bs = bias[colg];
      int rowb = mt * 16 + (lane >> 4) * 4;
      float* op = out + (long long)b * (NND * NH * HC) + colg;
#pragma unroll
      for (int r4 = 0; r4 < 4; ++r4) {
        int node = rowb + r4;
        if (node < NND) op[(long long)node * (NH * HC)] = a2[r4] + bs;
      }
    }
    __syncthreads();  // protect C1^T before next round overwrites
  }
}

extern "C" void kernel_launch(void* const* d_in, const int* in_sizes, int n_in,
                              void* d_out, int out_size, void* d_ws, size_t ws_size,
                              hipStream_t stream) {
  const float* x    = (const float*)d_in[0];
  const float* W    = (const float*)d_in[1];
  const float* e    = (const float*)d_in[2];
  const float* bias = (const float*)d_in[3];
  // d_in[4] = rows: unused (fixed pattern: row i owns edges i*K .. i*K+K-1)
  const int* cols   = (const int*)d_in[5];
  float* out        = (float*)d_out;

  bf16* Wp  = (bf16*)d_ws;
  bf16* M2d = (bf16*)((char*)d_ws + WS_M2D_OFF);
  bf16* M2p = (bf16*)((char*)d_ws + WS_M2P_OFF);

  int B = in_sizes[0] / (NND * CIN);  // 1024

  prep_wp_kernel<<<64, 256, 0, stream>>>(W, Wp);
  prep_zero_kernel<<<(NH * M2ROWS * M2K / 2 + 255) / 256, 256, 0, stream>>>((unsigned int*)M2d);
  prep_scatter_kernel<<<2, 256, 0, stream>>>(e, cols, M2d);
  prep_m2p_kernel<<<(NH * 7 * 7 * 64 + 255) / 256, 256, 0, stream>>>(M2d, M2p);
  semgconv_kernel<<<B, 1024, 0, stream>>>(x, bias, Wp, M2p, out);
}